// Round 7
// baseline (2253.756 us; speedup 1.0000x reference)
//
#include <hip/hip_runtime.h>

// Problem constants (fixed by setup_inputs)
constexpr int NPTS = 16384;
constexpr int KNB  = 9;
constexpr int CDIM = 16;
constexpr int HDIM = 32;

// Spatial grid: FIXED bounds (data ~ N(0,1)). Outliers clamp into edge cells;
// search stays EXACT: edge cells own all points beyond the boundary, and a
// clipped side contributes no uncovered region (FBIG) once the scanned block
// reaches the grid edge.
constexpr int   G    = 128;
constexpr int   GC   = G * G;            // 16384 cells
constexpr float GMIN = -3.3f;
constexpr float GMAX =  3.3f;
constexpr float CW   = (GMAX - GMIN) / G;
constexpr float INVW = G / (GMAX - GMIN);
constexpr float FBIG = 3.0e38f;

// ---------------------------------------------------------------------------
// Register-resident top-9 (smallest d2). Arrays indexed only with
// compile-time constants -> stay in VGPRs.
// ---------------------------------------------------------------------------
struct TopK {
    float d[KNB];
    int   id[KNB];
    float dw;

    __device__ __forceinline__ void init() {
#pragma unroll
        for (int s = 0; s < KNB; ++s) { d[s] = FBIG; id[s] = -1; }
        dw = FBIG;
    }
    __device__ __forceinline__ void push(float d2, int j) {
        if (d2 < dw) {
            bool done = false;
#pragma unroll
            for (int s = 0; s < KNB; ++s) {
                bool m = (!done) && (d[s] == dw);
                d[s]  = m ? d2 : d[s];
                id[s] = m ? j  : id[s];
                done  = done || m;
            }
            float m0 = fmaxf(fmaxf(d[0], d[1]), d[2]);
            float m1 = fmaxf(fmaxf(d[3], d[4]), d[5]);
            float m2 = fmaxf(fmaxf(d[6], d[7]), d[8]);
            dw = fmaxf(fmaxf(m0, m1), m2);
        }
    }
};

__device__ __forceinline__ int clampG(int c) { return min(G - 1, max(0, c)); }

// ---------------------------------------------------------------------------
// Bin count (fixed box). 256 blocks x 64 threads.
// ---------------------------------------------------------------------------
__global__ __launch_bounds__(64) void bin_count(const float* __restrict__ x,
                                                int* __restrict__ cnt,
                                                int* __restrict__ cellOf) {
    const int i = blockIdx.x * 64 + threadIdx.x;
    const float2 p = *reinterpret_cast<const float2*>(x + (size_t)i * CDIM);
    const int cx = clampG((int)((p.x - GMIN) * INVW));
    const int cy = clampG((int)((p.y - GMIN) * INVW));
    const int c = cy * G + cx;
    cellOf[i] = c;
    atomicAdd(&cnt[c], 1);
}

// ---------------------------------------------------------------------------
// Exclusive scan over GC=16384 counts (1 block of 1024). Also RE-ZEROS cnt
// (ready for the next step's bin_count) — no per-step memsets.
// ---------------------------------------------------------------------------
__global__ __launch_bounds__(1024) void scan_kernel(int* __restrict__ cnt,
                                                    unsigned short* __restrict__ cs16,
                                                    int* __restrict__ cursor) {
    __shared__ int S[1024];
    const int t = threadIdx.x;
    const int base = t * 16;
    int loc[16];
    int sum = 0;
#pragma unroll
    for (int k = 0; k < 16; ++k) { loc[k] = sum; sum += cnt[base + k]; cnt[base + k] = 0; }
    S[t] = sum;
    __syncthreads();
    for (int off = 1; off < 1024; off <<= 1) {
        const int v = (t >= off) ? S[t - off] : 0;
        __syncthreads();
        S[t] += v;
        __syncthreads();
    }
    const int excl = S[t] - sum;
#pragma unroll
    for (int k = 0; k < 16; ++k) {
        const int v = excl + loc[k];
        cs16[base + k] = (unsigned short)v;
        cursor[base + k] = v;
    }
}

// ---------------------------------------------------------------------------
// Scatter into binned order: coords (float2), original id, feature row.
// ---------------------------------------------------------------------------
__global__ __launch_bounds__(64) void scatter_kernel(const float* __restrict__ x,
                                                     const int* __restrict__ cellOf,
                                                     int* __restrict__ cursor,
                                                     float2* __restrict__ bxy,
                                                     int* __restrict__ bid,
                                                     float* __restrict__ xb) {
    const int i = blockIdx.x * 64 + threadIdx.x;
    const int c = cellOf[i];
    const int pos = atomicAdd(&cursor[c], 1);
    const float4* src = reinterpret_cast<const float4*>(x + (size_t)i * CDIM);
    float4* dst = reinterpret_cast<float4*>(xb + (size_t)pos * CDIM);
    const float4 v0 = src[0];
    dst[0] = v0; dst[1] = src[1]; dst[2] = src[2]; dst[3] = src[3];
    bxy[pos] = make_float2(v0.x, v0.y);
    bid[pos] = i;
}

// ---------------------------------------------------------------------------
// Exact kNN, one lane per point, NO straggler pass: the scanned square
// doubles (r -> 2r) until the 9-NN bound converges. Expansion is duplicate-
// free: new full-width rows are one contiguous span each (2 LDS lookups);
// already-scanned rows get two side-segment spans. A tail point at radius R
// cells costs ~4R span lookups (~300 LDS reads worst case) instead of a
// 16384-candidate brute force. Bulk points still converge at r=1..2.
// 64 blocks x 256 threads (4 waves/SIMD for latency hiding).
// ---------------------------------------------------------------------------
__global__ __launch_bounds__(256) void knn_search(const float2* __restrict__ bxy,
                                                  const unsigned short* __restrict__ cs16,
                                                  int* __restrict__ nb) {
    __shared__ unsigned short sCS[GC + 2];

    // Cooperative LDS load of the span table: 2048 uint4 = 16384 u16.
    {
        const uint4* src = reinterpret_cast<const uint4*>(cs16);
        uint4* dst = reinterpret_cast<uint4*>(sCS);
#pragma unroll
        for (int k = 0; k < 8; ++k) dst[threadIdx.x + 256 * k] = src[threadIdx.x + 256 * k];
        if (threadIdx.x == 0) sCS[GC] = (unsigned short)NPTS;
    }
    __syncthreads();

    const int p = blockIdx.x * 256 + threadIdx.x;
    const float2 q = bxy[p];
    const float qx = q.x, qy = q.y;
    const int cx = clampG((int)((qx - GMIN) * INVW));
    const int cy = clampG((int)((qy - GMIN) * INVW));

    TopK tk; tk.init();

    auto scan_span = [&](int s, int e) {
        for (int i = s; i < e; ++i) {
            const float2 pt = bxy[i];
            const float dx = qx - pt.x;
            const float dy = qy - pt.y;
            tk.push(fmaf(dx, dx, dy * dy), i);
        }
    };
    auto row_span = [&](int y, int x0, int x1) {
        if (y < 0 || y >= G) return;
        x0 = max(x0, 0); x1 = min(x1, G - 1);
        if (x0 > x1) return;
        scan_span((int)sCS[y * G + x0], (int)sCS[y * G + x1 + 1]);
    };

    // r=1 block (3x3)
    row_span(cy - 1, cx - 1, cx + 1);
    row_span(cy,     cx - 1, cx + 1);
    row_span(cy + 1, cx - 1, cx + 1);

    int ro = 1;                           // scanned square: [cy±ro] x [cx±ro]
    while (true) {
        const float dl = (cx - ro >= 0) ? fmaxf(qx - (GMIN + (float)(cx - ro) * CW), 0.0f) : FBIG;
        const float dr = (cx + ro <  G) ? fmaxf((GMIN + (float)(cx + ro + 1) * CW) - qx, 0.0f) : FBIG;
        const float db = (cy - ro >= 0) ? fmaxf(qy - (GMIN + (float)(cy - ro) * CW), 0.0f) : FBIG;
        const float dt = (cy + ro <  G) ? fmaxf((GMIN + (float)(cy + ro + 1) * CW) - qy, 0.0f) : FBIG;
        const float dmin = fminf(fminf(dl, dr), fminf(db, dt));
        if (tk.dw < FBIG && tk.dw <= dmin * dmin) break;
        if (ro >= G) break;               // whole grid covered — exact fallback

        const int rn = min(ro * 2, G);
        // new full-width rows above and below
        for (int y = cy - rn; y <= cy - ro - 1; ++y) row_span(y, cx - rn, cx + rn);
        for (int y = cy + ro + 1; y <= cy + rn; ++y) row_span(y, cx - rn, cx + rn);
        // side segments on already-scanned rows
        for (int y = cy - ro; y <= cy + ro; ++y) {
            row_span(y, cx - rn, cx - ro - 1);
            row_span(y, cx + ro + 1, cx + rn);
        }
        ro = rn;
    }

#pragma unroll
    for (int s = 0; s < KNB; ++s) nb[p * KNB + s] = tk.id[s];
}

// ---------------------------------------------------------------------------
// GCN layer in binned order, thread per point, 256 blocks x 64 threads
// (all 256 CUs). FINAL fuses residual and scatters back via bid.
// ---------------------------------------------------------------------------
template <int CIN, int COUT, bool RELU, bool FINAL>
__global__ __launch_bounds__(64) void gcn_layer(const float* __restrict__ hin,
                                                const int* __restrict__ nb,
                                                const float* __restrict__ W,
                                                const float* __restrict__ xb,
                                                const int* __restrict__ bid,
                                                float* __restrict__ hout) {
    const int n = blockIdx.x * 64 + threadIdx.x;

    float agg[CIN];
#pragma unroll
    for (int c = 0; c < CIN; ++c) agg[c] = 0.0f;

#pragma unroll
    for (int k = 0; k < KNB; ++k) {
        const int j = nb[n * KNB + k];
        const float4* r = reinterpret_cast<const float4*>(hin + (size_t)j * CIN);
#pragma unroll
        for (int c4 = 0; c4 < CIN / 4; ++c4) {
            const float4 v = r[c4];
            agg[4 * c4 + 0] += v.x;
            agg[4 * c4 + 1] += v.y;
            agg[4 * c4 + 2] += v.z;
            agg[4 * c4 + 3] += v.w;
        }
    }
#pragma unroll
    for (int c = 0; c < CIN; ++c) agg[c] *= (1.0f / 9.0f);

    const int outrow = FINAL ? bid[n] : n;
#pragma unroll
    for (int o = 0; o < COUT; ++o) {
        float acc = 0.0f;
#pragma unroll
        for (int c = 0; c < CIN; ++c) acc = fmaf(agg[c], W[c * COUT + o], acc);
        if (RELU)  acc = fmaxf(acc, 0.0f);
        if (FINAL) acc = xb[n * COUT + o] + 1e-4f * acc;
        hout[outrow * COUT + o] = acc;
    }
}

// ---------------------------------------------------------------------------
// 2 fixed steps x 8 dispatches: bin_count, scan, scatter, knn_search, 4x gcn.
// ---------------------------------------------------------------------------
extern "C" void kernel_launch(void* const* d_in, const int* in_sizes, int n_in,
                              void* d_out, int out_size, void* d_ws, size_t ws_size,
                              hipStream_t stream) {
    const float* seed = (const float*)d_in[0];
    const float* W1   = (const float*)d_in[1];
    const float* W2   = (const float*)d_in[2];
    const float* W3   = (const float*)d_in[3];
    const float* W4   = (const float*)d_in[4];
    float* out = (float*)d_out;

    char* ws = (char*)d_ws;
    size_t off = 0;
    auto alloc = [&](size_t bytes) -> void* {
        void* p = ws + off;
        off += (bytes + 255) & ~(size_t)255;
        return p;
    };
    int*            cnt    = (int*)   alloc(GC * sizeof(int));
    unsigned short* cs16   = (unsigned short*)alloc((GC + 16) * sizeof(unsigned short));
    int*            cursor = (int*)   alloc(GC * sizeof(int));
    int*            cellOf = (int*)   alloc(NPTS * sizeof(int));
    float2*         bxy    = (float2*)alloc((size_t)NPTS * sizeof(float2));
    int*            bid    = (int*)   alloc(NPTS * sizeof(int));
    float*          xb     = (float*) alloc((size_t)NPTS * CDIM * sizeof(float));
    int*            nb     = (int*)   alloc((size_t)NPTS * KNB * sizeof(int));
    float*          hA     = (float*) alloc((size_t)NPTS * HDIM * sizeof(float));
    float*          hB     = (float*) alloc((size_t)NPTS * HDIM * sizeof(float));
    float*          x1     = (float*) alloc((size_t)NPTS * CDIM * sizeof(float));

    constexpr int NB64 = NPTS / 64;     // 256 blocks of 64

    // cnt must be zero before step-0 bin_count (ws is poisoned each call);
    // scan_kernel re-zeros it for the next step.
    hipMemsetAsync(cnt, 0, GC * sizeof(int), stream);

    for (int step = 0; step < 2; ++step) {
        const float* xin  = (step == 0) ? seed : x1;
        float*       xout = (step == 0) ? x1   : out;

        bin_count     <<<NB64, 64, 0, stream>>>(xin, cnt, cellOf);
        scan_kernel   <<<1, 1024, 0, stream>>>(cnt, cs16, cursor);
        scatter_kernel<<<NB64, 64, 0, stream>>>(xin, cellOf, cursor, bxy, bid, xb);
        knn_search    <<<64, 256, 0, stream>>>(bxy, cs16, nb);

        gcn_layer<CDIM, HDIM, true,  false><<<NB64, 64, 0, stream>>>(xb, nb, W1, nullptr, nullptr, hA);
        gcn_layer<HDIM, HDIM, true,  false><<<NB64, 64, 0, stream>>>(hA, nb, W2, nullptr, nullptr, hB);
        gcn_layer<HDIM, HDIM, true,  false><<<NB64, 64, 0, stream>>>(hB, nb, W3, nullptr, nullptr, hA);
        gcn_layer<HDIM, CDIM, false, true ><<<NB64, 64, 0, stream>>>(hA, nb, W4, xb, bid, xout);
    }
}